// Round 1
// baseline (322.535 us; speedup 1.0000x reference)
//
#include <hip/hip_runtime.h>

#define B 256
#define D 256
#define N 200000
#define C 1000

// ---------------- ws layout (bytes) ----------------
// sums     : C*D f32   @ 0          (1,024,000)
// new_rows : B*D f32   @ 1,024,000  (  262,144)
// override : N   int   @ 1,286,144  (  800,000)
// cnts     : C   int   @ 2,086,144  (    4,000)
// touched  : C   int   @ 2,090,144  (    4,000)
#define WS_SUMS_OFF     0
#define WS_NEWROWS_OFF  1024000
#define WS_OVERRIDE_OFF 1286144
#define WS_CNTS_OFF     2086144
#define WS_TOUCHED_OFF  2090144

// Zero/neg-init all scratch (ws is poisoned 0xAA and never re-poisoned).
__global__ void init_kernel(int* __restrict__ override_, float* __restrict__ sums,
                            int* __restrict__ cnts, int* __restrict__ touched) {
    int i = blockIdx.x * 256 + threadIdx.x;
    const int total = N + C * D + C + C;
    if (i >= total) return;
    if (i < N) {
        override_[i] = -1;
    } else if (i < N + C * D) {
        sums[i - N] = 0.0f;
    } else if (i < N + C * D + C) {
        cnts[i - N - C * D] = 0;
    } else {
        touched[i - N - C * D - C] = 0;
    }
}

// new_rows[b] = l2norm(0.5*features[indexes[b]] + 0.5*inputs[b])
__global__ __launch_bounds__(256) void new_rows_kernel(
    const float* __restrict__ inputs, const float* __restrict__ features,
    const int* __restrict__ indexes, float* __restrict__ new_rows) {
    int b = blockIdx.x;
    int d = threadIdx.x;
    int r = indexes[b];
    float x = 0.5f * features[(size_t)r * D + d] + 0.5f * inputs[b * D + d];
    float s = x * x;
    #pragma unroll
    for (int off = 32; off > 0; off >>= 1) s += __shfl_down(s, off);
    __shared__ float wpart[4];
    __shared__ float stot;
    if ((threadIdx.x & 63) == 0) wpart[threadIdx.x >> 6] = s;
    __syncthreads();
    if (threadIdx.x == 0) stot = (wpart[0] + wpart[1]) + (wpart[2] + wpart[3]);
    __syncthreads();
    new_rows[b * D + d] = x / sqrtf(stot + 1e-12f);
}

// Resolve duplicate scatter indices (last write wins) + mark touched clusters.
__global__ void prep_kernel(const int* __restrict__ indexes, const int* __restrict__ targets,
                            int* __restrict__ override_, int* __restrict__ touched) {
    __shared__ int sidx[B];
    int i = threadIdx.x;
    sidx[i] = indexes[i];
    __syncthreads();
    bool win = true;
    for (int j = i + 1; j < B; ++j) {
        if (sidx[j] == sidx[i]) { win = false; break; }
    }
    if (win) override_[sidx[i]] = i;
    touched[targets[i]] = 1;
}

// Fused: feats = scatter(features, new_rows); accumulate segment sums/counts
// for touched clusters. One wave per row (64 lanes x float4 = 256 floats).
__global__ __launch_bounds__(256) void feats_kernel(
    const float4* __restrict__ features, const int* __restrict__ labels,
    const int* __restrict__ override_, const int* __restrict__ touched,
    const float4* __restrict__ new_rows, float4* __restrict__ out_feats,
    float* __restrict__ sums, int* __restrict__ cnts) {
    int wave = threadIdx.x >> 6;
    int lane = threadIdx.x & 63;
    int row = blockIdx.x * 4 + wave;
    if (row >= N) return;
    int ov = override_[row];
    const float4* src = (ov >= 0) ? (new_rows + (size_t)ov * 64)
                                  : (features + (size_t)row * 64);
    float4 v = src[lane];
    out_feats[(size_t)row * 64 + lane] = v;
    int lab = labels[row];
    if (touched[lab]) {
        float* s = sums + (size_t)lab * D + lane * 4;
        atomicAdd(s + 0, v.x);
        atomicAdd(s + 1, v.y);
        atomicAdd(s + 2, v.z);
        atomicAdd(s + 3, v.w);
        if (lane == 0) atomicAdd(&cnts[lab], 1);
    }
}

// new_cluster_mean[c] = touched ? sums[c]/max(cnt,1) : cluster_mean[c]
__global__ __launch_bounds__(256) void means_kernel(
    const float* __restrict__ cluster_mean, const float* __restrict__ sums,
    const int* __restrict__ cnts, const int* __restrict__ touched,
    float* __restrict__ out_cm) {
    int c = blockIdx.x;
    int d = threadIdx.x;
    float out;
    if (touched[c]) {
        out = sums[(size_t)c * D + d] / fmaxf((float)cnts[c], 1.0f);
    } else {
        out = cluster_mean[(size_t)c * D + d];
    }
    out_cm[(size_t)c * D + d] = out;
}

// logits[b, :] = inputs[b] @ cluster_mean.T   (f32 VALU, L2-resident operands)
__global__ __launch_bounds__(256) void logits_kernel(
    const float* __restrict__ inputs, const float* __restrict__ cluster_mean,
    float* __restrict__ out0) {
    __shared__ float sin_[D];
    int b = blockIdx.x;
    sin_[threadIdx.x] = inputs[b * D + threadIdx.x];
    __syncthreads();
    for (int c = threadIdx.x; c < C; c += 256) {
        const float4* cm = (const float4*)(cluster_mean + (size_t)c * D);
        float a0 = 0.f, a1 = 0.f, a2 = 0.f, a3 = 0.f;
        #pragma unroll 8
        for (int d4 = 0; d4 < 64; ++d4) {
            float4 v = cm[d4];
            const float* si = sin_ + d4 * 4;
            a0 += v.x * si[0];
            a1 += v.y * si[1];
            a2 += v.z * si[2];
            a3 += v.w * si[3];
        }
        out0[(size_t)b * C + c] = (a0 + a1) + (a2 + a3);
    }
}

extern "C" void kernel_launch(void* const* d_in, const int* in_sizes, int n_in,
                              void* d_out, int out_size, void* d_ws, size_t ws_size,
                              hipStream_t stream) {
    const float* inputs       = (const float*)d_in[0];
    const float* features     = (const float*)d_in[1];
    const float* cluster_mean = (const float*)d_in[2];
    const int*   indexes      = (const int*)d_in[3];
    const int*   labels       = (const int*)d_in[4];
    const int*   targets      = (const int*)d_in[5];

    float* out_logits = (float*)d_out;                      // B*C
    float* out_feats  = out_logits + (size_t)B * C;         // N*D
    float* out_cm     = out_feats + (size_t)N * D;          // C*D

    char* ws = (char*)d_ws;
    float* sums     = (float*)(ws + WS_SUMS_OFF);
    float* new_rows = (float*)(ws + WS_NEWROWS_OFF);
    int*   override_= (int*)(ws + WS_OVERRIDE_OFF);
    int*   cnts     = (int*)(ws + WS_CNTS_OFF);
    int*   touched  = (int*)(ws + WS_TOUCHED_OFF);

    const int init_total = N + C * D + C + C;
    init_kernel<<<(init_total + 255) / 256, 256, 0, stream>>>(override_, sums, cnts, touched);
    new_rows_kernel<<<B, 256, 0, stream>>>(inputs, features, indexes, new_rows);
    prep_kernel<<<1, B, 0, stream>>>(indexes, targets, override_, touched);
    feats_kernel<<<(N + 3) / 4, 256, 0, stream>>>(
        (const float4*)features, labels, override_, touched,
        (const float4*)new_rows, (float4*)out_feats, sums, cnts);
    means_kernel<<<C, 256, 0, stream>>>(cluster_mean, sums, cnts, touched, out_cm);
    logits_kernel<<<B, 256, 0, stream>>>(inputs, cluster_mean, out_logits);
}

// Round 2
// 248.841 us; speedup vs baseline: 1.2961x; 1.2961x over previous
//
#include <hip/hip_runtime.h>

#define B 256
#define D 256
#define N 200000
#define C 1000

// ---------------- ws layout (bytes) ----------------
#define WS_NEWROWS_OFF  0          // B*D f32      = 262144
#define WS_OVERRIDE_OFF 262144     // N int        = 800000
#define WS_HIST_OFF     1062144    // C int        = 4000
#define WS_OFFS_OFF     1066144    // C int        = 4000
#define WS_FILLPOS_OFF  1070144    // C int        = 4000
#define WS_TOUCHED_OFF  1074144    // C int        = 4000
#define WS_ROWLIST_OFF  1078144    // N int        = 800000  -> total 1,878,144

// Zero hist + touched (2*C ints). ws is poisoned 0xAA once, never re-poisoned.
__global__ void zero_kernel(int* __restrict__ hist, int* __restrict__ touched) {
    int i = blockIdx.x * 256 + threadIdx.x;
    if (i < C) hist[i] = 0;
    else if (i < 2 * C) touched[i - C] = 0;
}

// override_[i] = -1 for all rows; histogram of labels.
__global__ void histinit_kernel(const int* __restrict__ labels,
                                int* __restrict__ override_, int* __restrict__ hist) {
    int i = blockIdx.x * 256 + threadIdx.x;
    if (i >= N) return;
    override_[i] = -1;
    atomicAdd(&hist[labels[i]], 1);
}

// new_rows[b] = l2norm(0.5*features[indexes[b]] + 0.5*inputs[b])
__global__ __launch_bounds__(256) void new_rows_kernel(
    const float* __restrict__ inputs, const float* __restrict__ features,
    const int* __restrict__ indexes, float* __restrict__ new_rows) {
    int b = blockIdx.x;
    int d = threadIdx.x;
    int r = indexes[b];
    float x = 0.5f * features[(size_t)r * D + d] + 0.5f * inputs[b * D + d];
    float s = x * x;
    #pragma unroll
    for (int off = 32; off > 0; off >>= 1) s += __shfl_down(s, off);
    __shared__ float wpart[4];
    __shared__ float stot;
    if ((threadIdx.x & 63) == 0) wpart[threadIdx.x >> 6] = s;
    __syncthreads();
    if (threadIdx.x == 0) stot = (wpart[0] + wpart[1]) + (wpart[2] + wpart[3]);
    __syncthreads();
    new_rows[b * D + d] = x / sqrtf(stot + 1e-12f);
}

// Resolve duplicate scatter indices (last write wins) + mark touched clusters.
__global__ void prep_kernel(const int* __restrict__ indexes, const int* __restrict__ targets,
                            int* __restrict__ override_, int* __restrict__ touched) {
    __shared__ int sidx[B];
    int i = threadIdx.x;
    sidx[i] = indexes[i];
    __syncthreads();
    bool win = true;
    for (int j = i + 1; j < B; ++j) {
        if (sidx[j] == sidx[i]) { win = false; break; }
    }
    if (win) override_[sidx[i]] = i;
    touched[targets[i]] = 1;
}

// Exclusive prefix scan of hist[0..C) -> offs; also copy to fillpos.
// One block, 256 threads, 4 bins/thread (1024 >= C).
__global__ __launch_bounds__(256) void scan_kernel(
    const int* __restrict__ hist, int* __restrict__ offs, int* __restrict__ fillpos) {
    __shared__ int warp_tot[4];
    int t = threadIdx.x;
    int base = t * 4;
    int h0 = (base + 0 < C) ? hist[base + 0] : 0;
    int h1 = (base + 1 < C) ? hist[base + 1] : 0;
    int h2 = (base + 2 < C) ? hist[base + 2] : 0;
    int h3 = (base + 3 < C) ? hist[base + 3] : 0;
    int tot = h0 + h1 + h2 + h3;
    int lane = t & 63;
    int scan = tot;
    #pragma unroll
    for (int off = 1; off < 64; off <<= 1) {
        int v = __shfl_up(scan, off);
        if (lane >= off) scan += v;
    }
    if (lane == 63) warp_tot[t >> 6] = scan;
    __syncthreads();
    int w = t >> 6;
    int wbase = 0;
    for (int i = 0; i < w; ++i) wbase += warp_tot[i];
    int excl = wbase + scan - tot;
    if (base + 0 < C) { offs[base + 0] = excl;                fillpos[base + 0] = excl; }
    if (base + 1 < C) { offs[base + 1] = excl + h0;           fillpos[base + 1] = excl + h0; }
    if (base + 2 < C) { offs[base + 2] = excl + h0 + h1;      fillpos[base + 2] = excl + h0 + h1; }
    if (base + 3 < C) { offs[base + 3] = excl + h0 + h1 + h2; fillpos[base + 3] = excl + h0 + h1 + h2; }
}

// Scatter row ids of touched clusters into per-cluster contiguous lists.
__global__ void fill_kernel(const int* __restrict__ labels, const int* __restrict__ touched,
                            int* __restrict__ fillpos, int* __restrict__ rowlist) {
    int i = blockIdx.x * 256 + threadIdx.x;
    if (i >= N) return;
    int lab = labels[i];
    if (touched[lab]) {
        int p = atomicAdd(&fillpos[lab], 1);
        rowlist[p] = i;
    }
}

// Pure streaming copy with per-row override. One wave per row (64 x float4).
__global__ __launch_bounds__(256) void feats_copy_kernel(
    const float4* __restrict__ features, const int* __restrict__ override_,
    const float4* __restrict__ new_rows, float4* __restrict__ out_feats) {
    int wave = threadIdx.x >> 6;
    int lane = threadIdx.x & 63;
    int row = blockIdx.x * 4 + wave;
    if (row >= N) return;
    int ov = override_[row];
    const float4* src = (ov >= 0) ? (new_rows + (size_t)ov * 64)
                                  : (features + (size_t)row * 64);
    out_feats[(size_t)row * 64 + lane] = src[lane];
}

// Per-cluster mean: touched clusters sum their row list (no atomics);
// untouched clusters copy cluster_mean.
__global__ __launch_bounds__(256) void cm_kernel(
    const float* __restrict__ cluster_mean, const float* __restrict__ features,
    const float* __restrict__ new_rows, const int* __restrict__ override_,
    const int* __restrict__ touched, const int* __restrict__ hist,
    const int* __restrict__ offs, const int* __restrict__ rowlist,
    float* __restrict__ out_cm) {
    int c = blockIdx.x;
    int d = threadIdx.x;
    if (!touched[c]) {
        out_cm[(size_t)c * D + d] = cluster_mean[(size_t)c * D + d];
        return;
    }
    int cnt = hist[c];
    int off = offs[c];
    __shared__ int srows[256];
    __shared__ int sov[256];
    float acc = 0.0f;
    for (int cs = 0; cs < cnt; cs += 256) {
        int k = cs + d;
        if (k < cnt) {
            int r = rowlist[off + k];
            srows[d] = r;
            sov[d] = override_[r];
        }
        __syncthreads();
        int m = min(256, cnt - cs);
        for (int j = 0; j < m; ++j) {
            int row = srows[j];
            int ov = sov[j];
            const float* src = (ov >= 0) ? (new_rows + (size_t)ov * D)
                                         : (features + (size_t)row * D);
            acc += src[d];
        }
        __syncthreads();
    }
    out_cm[(size_t)c * D + d] = acc / fmaxf((float)cnt, 1.0f);
}

// logits[b, :] = inputs[b] @ cluster_mean.T   (f32 VALU, L2/L3-resident operands)
__global__ __launch_bounds__(256) void logits_kernel(
    const float* __restrict__ inputs, const float* __restrict__ cluster_mean,
    float* __restrict__ out0) {
    __shared__ float sin_[D];
    int b = blockIdx.x;
    sin_[threadIdx.x] = inputs[b * D + threadIdx.x];
    __syncthreads();
    for (int c = threadIdx.x; c < C; c += 256) {
        const float4* cm = (const float4*)(cluster_mean + (size_t)c * D);
        float a0 = 0.f, a1 = 0.f, a2 = 0.f, a3 = 0.f;
        #pragma unroll 8
        for (int d4 = 0; d4 < 64; ++d4) {
            float4 v = cm[d4];
            const float* si = sin_ + d4 * 4;
            a0 += v.x * si[0];
            a1 += v.y * si[1];
            a2 += v.z * si[2];
            a3 += v.w * si[3];
        }
        out0[(size_t)b * C + c] = (a0 + a1) + (a2 + a3);
    }
}

extern "C" void kernel_launch(void* const* d_in, const int* in_sizes, int n_in,
                              void* d_out, int out_size, void* d_ws, size_t ws_size,
                              hipStream_t stream) {
    const float* inputs       = (const float*)d_in[0];
    const float* features     = (const float*)d_in[1];
    const float* cluster_mean = (const float*)d_in[2];
    const int*   indexes      = (const int*)d_in[3];
    const int*   labels       = (const int*)d_in[4];
    const int*   targets      = (const int*)d_in[5];

    float* out_logits = (float*)d_out;                      // B*C
    float* out_feats  = out_logits + (size_t)B * C;         // N*D
    float* out_cm     = out_feats + (size_t)N * D;          // C*D

    char* ws = (char*)d_ws;
    float* new_rows = (float*)(ws + WS_NEWROWS_OFF);
    int*   override_= (int*)(ws + WS_OVERRIDE_OFF);
    int*   hist     = (int*)(ws + WS_HIST_OFF);
    int*   offs     = (int*)(ws + WS_OFFS_OFF);
    int*   fillpos  = (int*)(ws + WS_FILLPOS_OFF);
    int*   touched  = (int*)(ws + WS_TOUCHED_OFF);
    int*   rowlist  = (int*)(ws + WS_ROWLIST_OFF);

    logits_kernel<<<B, 256, 0, stream>>>(inputs, cluster_mean, out_logits);
    zero_kernel<<<(2 * C + 255) / 256, 256, 0, stream>>>(hist, touched);
    histinit_kernel<<<(N + 255) / 256, 256, 0, stream>>>(labels, override_, hist);
    new_rows_kernel<<<B, 256, 0, stream>>>(inputs, features, indexes, new_rows);
    prep_kernel<<<1, B, 0, stream>>>(indexes, targets, override_, touched);
    scan_kernel<<<1, 256, 0, stream>>>(hist, offs, fillpos);
    fill_kernel<<<(N + 255) / 256, 256, 0, stream>>>(labels, touched, fillpos, rowlist);
    feats_copy_kernel<<<(N + 3) / 4, 256, 0, stream>>>(
        (const float4*)features, override_, (const float4*)new_rows, (float4*)out_feats);
    cm_kernel<<<C, 256, 0, stream>>>(cluster_mean, features, new_rows, override_,
                                     touched, hist, offs, rowlist, out_cm);
}

// Round 3
// 231.959 us; speedup vs baseline: 1.3905x; 1.0728x over previous
//
#include <hip/hip_runtime.h>

#define B 256
#define D 256
#define N 200000
#define C 1000
#define CM_CHUNKS 8

// ---------------- ws layout (bytes) ----------------
#define WS_NEWROWS_OFF  0          // B*D f32      = 262144
#define WS_OVERRIDE_OFF 262144     // N int        = 800000
#define WS_HIST_OFF     1062144    // C int        = 4000
#define WS_OFFS_OFF     1066144    // C int        = 4000
#define WS_FILLPOS_OFF  1070144    // C int        = 4000
#define WS_TOUCHED_OFF  1074144    // C int        = 4000
#define WS_SUMS_OFF     1078144    // C*D f32      = 1024000
#define WS_ROWLIST_OFF  2102144    // N int        = 800000  -> total 2,902,144

// Zero hist + touched + sums. ws is poisoned 0xAA once, never re-poisoned.
__global__ void zero_kernel(int* __restrict__ hist, int* __restrict__ touched,
                            float* __restrict__ sums) {
    int i = blockIdx.x * 256 + threadIdx.x;
    if (i < C) hist[i] = 0;
    else if (i < 2 * C) touched[i - C] = 0;
    else if (i < 2 * C + C * D) sums[i - 2 * C] = 0.0f;
}

// override_[i] = -1 for all rows; histogram of labels.
__global__ void histinit_kernel(const int* __restrict__ labels,
                                int* __restrict__ override_, int* __restrict__ hist) {
    int i = blockIdx.x * 256 + threadIdx.x;
    if (i >= N) return;
    override_[i] = -1;
    atomicAdd(&hist[labels[i]], 1);
}

// new_rows[b] = l2norm(0.5*features[indexes[b]] + 0.5*inputs[b])
__global__ __launch_bounds__(256) void new_rows_kernel(
    const float* __restrict__ inputs, const float* __restrict__ features,
    const int* __restrict__ indexes, float* __restrict__ new_rows) {
    int b = blockIdx.x;
    int d = threadIdx.x;
    int r = indexes[b];
    float x = 0.5f * features[(size_t)r * D + d] + 0.5f * inputs[b * D + d];
    float s = x * x;
    #pragma unroll
    for (int off = 32; off > 0; off >>= 1) s += __shfl_down(s, off);
    __shared__ float wpart[4];
    __shared__ float stot;
    if ((threadIdx.x & 63) == 0) wpart[threadIdx.x >> 6] = s;
    __syncthreads();
    if (threadIdx.x == 0) stot = (wpart[0] + wpart[1]) + (wpart[2] + wpart[3]);
    __syncthreads();
    new_rows[b * D + d] = x / sqrtf(stot + 1e-12f);
}

// Resolve duplicate scatter indices (last write wins) + mark touched clusters.
// Must run AFTER histinit_kernel (override_ ordering).
__global__ void prep_kernel(const int* __restrict__ indexes, const int* __restrict__ targets,
                            int* __restrict__ override_, int* __restrict__ touched) {
    __shared__ int sidx[B];
    int i = threadIdx.x;
    sidx[i] = indexes[i];
    __syncthreads();
    bool win = true;
    for (int j = i + 1; j < B; ++j) {
        if (sidx[j] == sidx[i]) { win = false; break; }
    }
    if (win) override_[sidx[i]] = i;
    touched[targets[i]] = 1;
}

// Exclusive prefix scan of hist[0..C) -> offs; also copy to fillpos.
__global__ __launch_bounds__(256) void scan_kernel(
    const int* __restrict__ hist, int* __restrict__ offs, int* __restrict__ fillpos) {
    __shared__ int warp_tot[4];
    int t = threadIdx.x;
    int base = t * 4;
    int h0 = (base + 0 < C) ? hist[base + 0] : 0;
    int h1 = (base + 1 < C) ? hist[base + 1] : 0;
    int h2 = (base + 2 < C) ? hist[base + 2] : 0;
    int h3 = (base + 3 < C) ? hist[base + 3] : 0;
    int tot = h0 + h1 + h2 + h3;
    int lane = t & 63;
    int scan = tot;
    #pragma unroll
    for (int off = 1; off < 64; off <<= 1) {
        int v = __shfl_up(scan, off);
        if (lane >= off) scan += v;
    }
    if (lane == 63) warp_tot[t >> 6] = scan;
    __syncthreads();
    int w = t >> 6;
    int wbase = 0;
    for (int i = 0; i < w; ++i) wbase += warp_tot[i];
    int excl = wbase + scan - tot;
    if (base + 0 < C) { offs[base + 0] = excl;                fillpos[base + 0] = excl; }
    if (base + 1 < C) { offs[base + 1] = excl + h0;           fillpos[base + 1] = excl + h0; }
    if (base + 2 < C) { offs[base + 2] = excl + h0 + h1;      fillpos[base + 2] = excl + h0 + h1; }
    if (base + 3 < C) { offs[base + 3] = excl + h0 + h1 + h2; fillpos[base + 3] = excl + h0 + h1 + h2; }
}

// Scatter row ids of touched clusters into per-cluster contiguous lists.
__global__ void fill_kernel(const int* __restrict__ labels, const int* __restrict__ touched,
                            int* __restrict__ fillpos, int* __restrict__ rowlist) {
    int i = blockIdx.x * 256 + threadIdx.x;
    if (i >= N) return;
    int lab = labels[i];
    if (touched[lab]) {
        int p = atomicAdd(&fillpos[lab], 1);
        rowlist[p] = i;
    }
}

// Pure streaming copy with per-row override. One wave per row (64 x float4).
__global__ __launch_bounds__(256) void feats_copy_kernel(
    const float4* __restrict__ features, const int* __restrict__ override_,
    const float4* __restrict__ new_rows, float4* __restrict__ out_feats) {
    int wave = threadIdx.x >> 6;
    int lane = threadIdx.x & 63;
    int row = blockIdx.x * 4 + wave;
    if (row >= N) return;
    int ov = override_[row];
    const float4* src = (ov >= 0) ? (new_rows + (size_t)ov * 64)
                                  : (features + (size_t)row * 64);
    out_feats[(size_t)row * 64 + lane] = src[lane];
}

// Parallel cluster sums: grid = C*CM_CHUNKS blocks. Block (c,k) register-
// accumulates rows k, k+8, k+16, ... of cluster c's row list, then flushes
// one f32 atomicAdd per thread into sums.
__global__ __launch_bounds__(256) void cm_sum_kernel(
    const float* __restrict__ features, const float* __restrict__ new_rows,
    const int* __restrict__ override_, const int* __restrict__ touched,
    const int* __restrict__ hist, const int* __restrict__ offs,
    const int* __restrict__ rowlist, float* __restrict__ sums) {
    int c = blockIdx.x / CM_CHUNKS;
    int k = blockIdx.x % CM_CHUNKS;
    if (!touched[c]) return;
    int cnt = hist[c];
    if (k >= cnt) return;
    int off = offs[c];
    int d = threadIdx.x;
    float acc = 0.0f;
    for (int j = k; j < cnt; j += CM_CHUNKS) {
        int r = rowlist[off + j];
        int ov = override_[r];
        const float* src = (ov >= 0) ? (new_rows + (size_t)ov * D)
                                     : (features + (size_t)r * D);
        acc += src[d];
    }
    atomicAdd(&sums[(size_t)c * D + d], acc);
}

// new_cluster_mean[c] = touched ? sums[c]/max(cnt,1) : cluster_mean[c]
__global__ __launch_bounds__(256) void means_kernel(
    const float* __restrict__ cluster_mean, const float* __restrict__ sums,
    const int* __restrict__ hist, const int* __restrict__ touched,
    float* __restrict__ out_cm) {
    int c = blockIdx.x;
    int d = threadIdx.x;
    float out;
    if (touched[c]) {
        out = sums[(size_t)c * D + d] / fmaxf((float)hist[c], 1.0f);
    } else {
        out = cluster_mean[(size_t)c * D + d];
    }
    out_cm[(size_t)c * D + d] = out;
}

// logits[b, :] = inputs[b] @ cluster_mean.T   (f32 VALU, L2/L3-resident operands)
__global__ __launch_bounds__(256) void logits_kernel(
    const float* __restrict__ inputs, const float* __restrict__ cluster_mean,
    float* __restrict__ out0) {
    __shared__ float sin_[D];
    int b = blockIdx.x;
    sin_[threadIdx.x] = inputs[b * D + threadIdx.x];
    __syncthreads();
    for (int c = threadIdx.x; c < C; c += 256) {
        const float4* cm = (const float4*)(cluster_mean + (size_t)c * D);
        float a0 = 0.f, a1 = 0.f, a2 = 0.f, a3 = 0.f;
        #pragma unroll 8
        for (int d4 = 0; d4 < 64; ++d4) {
            float4 v = cm[d4];
            const float* si = sin_ + d4 * 4;
            a0 += v.x * si[0];
            a1 += v.y * si[1];
            a2 += v.z * si[2];
            a3 += v.w * si[3];
        }
        out0[(size_t)b * C + c] = (a0 + a1) + (a2 + a3);
    }
}

extern "C" void kernel_launch(void* const* d_in, const int* in_sizes, int n_in,
                              void* d_out, int out_size, void* d_ws, size_t ws_size,
                              hipStream_t stream) {
    const float* inputs       = (const float*)d_in[0];
    const float* features     = (const float*)d_in[1];
    const float* cluster_mean = (const float*)d_in[2];
    const int*   indexes      = (const int*)d_in[3];
    const int*   labels       = (const int*)d_in[4];
    const int*   targets      = (const int*)d_in[5];

    float* out_logits = (float*)d_out;                      // B*C
    float* out_feats  = out_logits + (size_t)B * C;         // N*D
    float* out_cm     = out_feats + (size_t)N * D;          // C*D

    char* ws = (char*)d_ws;
    float* new_rows = (float*)(ws + WS_NEWROWS_OFF);
    int*   override_= (int*)(ws + WS_OVERRIDE_OFF);
    int*   hist     = (int*)(ws + WS_HIST_OFF);
    int*   offs     = (int*)(ws + WS_OFFS_OFF);
    int*   fillpos  = (int*)(ws + WS_FILLPOS_OFF);
    int*   touched  = (int*)(ws + WS_TOUCHED_OFF);
    float* sums     = (float*)(ws + WS_SUMS_OFF);
    int*   rowlist  = (int*)(ws + WS_ROWLIST_OFF);

    logits_kernel<<<B, 256, 0, stream>>>(inputs, cluster_mean, out_logits);
    zero_kernel<<<(2 * C + C * D + 255) / 256, 256, 0, stream>>>(hist, touched, sums);
    histinit_kernel<<<(N + 255) / 256, 256, 0, stream>>>(labels, override_, hist);
    new_rows_kernel<<<B, 256, 0, stream>>>(inputs, features, indexes, new_rows);
    prep_kernel<<<1, B, 0, stream>>>(indexes, targets, override_, touched);
    scan_kernel<<<1, 256, 0, stream>>>(hist, offs, fillpos);
    fill_kernel<<<(N + 255) / 256, 256, 0, stream>>>(labels, touched, fillpos, rowlist);
    feats_copy_kernel<<<(N + 3) / 4, 256, 0, stream>>>(
        (const float4*)features, override_, (const float4*)new_rows, (float4*)out_feats);
    cm_sum_kernel<<<C * CM_CHUNKS, 256, 0, stream>>>(
        features, new_rows, override_, touched, hist, offs, rowlist, sums);
    means_kernel<<<C, 256, 0, stream>>>(cluster_mean, sums, hist, touched, out_cm);
}